// Round 14
// baseline (100.692 us; speedup 1.0000x reference)
//
#include <hip/hip_runtime.h>
#include <math.h>

// Problem constants (Qwen3-4B-like decode)
#define NB    32
#define HIDV  2560
#define HD    128
#define NQH   32
#define NKVH  8
// pool: (4096 pages, 16 slots, 8 kvh, 128 d)

typedef __bf16 bf16x8 __attribute__((ext_vector_type(8)));
typedef float  f32x4  __attribute__((ext_vector_type(4)));

__device__ __forceinline__ unsigned bfpack(float a, float b) {
  unsigned ua = __float_as_uint(a), ub = __float_as_uint(b);
  ua = (ua + 0x7FFFu + ((ua >> 16) & 1u)) >> 16;   // RNE to bf16
  ub = (ub + 0x7FFFu + ((ub >> 16) & 1u)) >> 16;
  return ua | (ub << 16);
}

// ---------------------------------------------------------------------------
// Partial GEMM body (R7-proven): P[kc0][b][f] = 2 slabs of 256 K each.
// Grid stays wide (>=256 blocks) — R6 lesson.
// ---------------------------------------------------------------------------
__device__ __forceinline__ void gemm_body(
    const float* __restrict__ X, const float* __restrict__ W,
    float* __restrict__ P, int N, int K, int f0, int kc0, int slabs, int t,
    unsigned short* Wl, unsigned short* Xl) {
  const int w = t >> 6, l = t & 63;
  const int rA = l & 15, kq = l >> 4;
  f32x4 acc0 = {0.f, 0.f, 0.f, 0.f}, acc1 = {0.f, 0.f, 0.f, 0.f};

  for (int s = 0; s < slabs; ++s) {
    const int kc = kc0 * slabs + s;
    if (s) __syncthreads();
    const float* Wg = W + (size_t)f0 * K + (size_t)kc * 256;
    #pragma unroll
    for (int i = 0; i < 16; ++i) {
      int idx = i * 256 + t;
      int row = idx >> 6, c4 = idx & 63;
      float4 w4 = *(const float4*)(Wg + (size_t)row * K + c4 * 4);
      *(uint2*)((char*)Wl + row * 528 + c4 * 8) =
          make_uint2(bfpack(w4.x, w4.y), bfpack(w4.z, w4.w));
    }
    const float* Xg = X + (size_t)kc * 256;
    #pragma unroll
    for (int i = 0; i < 8; ++i) {
      int idx = i * 256 + t;
      int row = idx >> 6, c4 = idx & 63;
      float4 x4 = *(const float4*)(Xg + (size_t)row * K + c4 * 4);
      *(uint2*)((char*)Xl + row * 528 + c4 * 8) =
          make_uint2(bfpack(x4.x, x4.y), bfpack(x4.z, x4.w));
    }
    __syncthreads();

    const char* pa0 = (const char*)Xl + rA * 528 + kq * 16;
    const char* pa1 = pa0 + 16 * 528;
    const char* pb  = (const char*)Wl + (w * 16 + rA) * 528 + kq * 16;
    #pragma unroll
    for (int ks = 0; ks < 8; ++ks) {
      bf16x8 a0 = *(const bf16x8*)(pa0 + ks * 64);
      bf16x8 a1 = *(const bf16x8*)(pa1 + ks * 64);
      bf16x8 bb = *(const bf16x8*)(pb  + ks * 64);
      acc0 = __builtin_amdgcn_mfma_f32_16x16x32_bf16(a0, bb, acc0, 0, 0, 0);
      acc1 = __builtin_amdgcn_mfma_f32_16x16x32_bf16(a1, bb, acc1, 0, 0, 0);
    }
  }
  const int fcol = f0 + w * 16 + rA;   // C/D: col=lane&15, row=(lane>>4)*4+j
  float* Pr = P + ((size_t)kc0 * 32) * N + fcol;
  #pragma unroll
  for (int j = 0; j < 4; ++j) {
    int b0 = kq * 4 + j;
    Pr[(size_t)b0 * N]        = acc0[j];
    Pr[(size_t)(b0 + 16) * N] = acc1[j];
  }
}

// Fused QKV projection (R7 verbatim): grid (96, 5), chunk = 512 K (2 slabs).
__global__ __launch_bounds__(256) void qkv_gemm(
    const float* __restrict__ X, const float* __restrict__ Wq,
    const float* __restrict__ Wk, const float* __restrict__ Wv,
    float* __restrict__ qp, float* __restrict__ kp, float* __restrict__ vp) {
  __shared__ __align__(16) unsigned short Wl[64 * 264];
  __shared__ __align__(16) unsigned short Xl[32 * 264];
  const int bx = blockIdx.x;
  const float* W; float* P; int N, f0;
  if (bx < 64)      { W = Wq; P = qp; N = 4096; f0 = bx * 64; }
  else if (bx < 80) { W = Wk; P = kp; N = 1024; f0 = (bx - 64) * 64; }
  else              { W = Wv; P = vp; N = 1024; f0 = (bx - 80) * 64; }
  gemm_body(X, W, P, N, 2560, f0, blockIdx.y, 2, threadIdx.x, Wl, Xl);
}

// ---------------------------------------------------------------------------
// o_proj GEMM with atomicAdd epilogue (R13-validated). grid (40, 8).
// y zeroed by a preceding memset node; 8 contention-free adds per element.
// ---------------------------------------------------------------------------
__global__ __launch_bounds__(256) void o_gemm_a(
    const float* __restrict__ X, const float* __restrict__ W,
    float* __restrict__ y) {
  __shared__ __align__(16) unsigned short Wl[64 * 264];
  __shared__ __align__(16) unsigned short Xl[32 * 264];
  const int t = threadIdx.x;
  const int K = 4096, f0 = blockIdx.x * 64, kc0 = blockIdx.y;
  const int w = t >> 6, l = t & 63;
  const int rA = l & 15, kq = l >> 4;
  f32x4 acc0 = {0.f, 0.f, 0.f, 0.f}, acc1 = {0.f, 0.f, 0.f, 0.f};

  for (int s = 0; s < 2; ++s) {
    const int kc = kc0 * 2 + s;
    if (s) __syncthreads();
    const float* Wg = W + (size_t)f0 * K + (size_t)kc * 256;
    #pragma unroll
    for (int i = 0; i < 16; ++i) {
      int idx = i * 256 + t;
      int row = idx >> 6, c4 = idx & 63;
      float4 w4 = *(const float4*)(Wg + (size_t)row * K + c4 * 4);
      *(uint2*)((char*)Wl + row * 528 + c4 * 8) =
          make_uint2(bfpack(w4.x, w4.y), bfpack(w4.z, w4.w));
    }
    const float* Xg = X + (size_t)kc * 256;
    #pragma unroll
    for (int i = 0; i < 8; ++i) {
      int idx = i * 256 + t;
      int row = idx >> 6, c4 = idx & 63;
      float4 x4 = *(const float4*)(Xg + (size_t)row * K + c4 * 4);
      *(uint2*)((char*)Xl + row * 528 + c4 * 8) =
          make_uint2(bfpack(x4.x, x4.y), bfpack(x4.z, x4.w));
    }
    __syncthreads();

    const char* pa0 = (const char*)Xl + rA * 528 + kq * 16;
    const char* pa1 = pa0 + 16 * 528;
    const char* pb  = (const char*)Wl + (w * 16 + rA) * 528 + kq * 16;
    #pragma unroll
    for (int ks = 0; ks < 8; ++ks) {
      bf16x8 a0 = *(const bf16x8*)(pa0 + ks * 64);
      bf16x8 a1 = *(const bf16x8*)(pa1 + ks * 64);
      bf16x8 bb = *(const bf16x8*)(pb  + ks * 64);
      acc0 = __builtin_amdgcn_mfma_f32_16x16x32_bf16(a0, bb, acc0, 0, 0, 0);
      acc1 = __builtin_amdgcn_mfma_f32_16x16x32_bf16(a1, bb, acc1, 0, 0, 0);
    }
  }
  const int fcol = f0 + w * 16 + rA;
  float* Yr = y + fcol;
  #pragma unroll
  for (int j = 0; j < 4; ++j) {
    int b0 = kq * 4 + j;
    atomicAdd(&Yr[(size_t)b0 * 2560],        acc0[j]);
    atomicAdd(&Yr[(size_t)(b0 + 16) * 2560], acc1[j]);
  }
}

// ---------------------------------------------------------------------------
// Reduce 5 K-split partials + RMSNorm (q,k) + RoPE (q,k). grid=(32,48), blk=128.
// (R7 verbatim — standalone; the fused-prologue variant was slower, R13.)
// ---------------------------------------------------------------------------
__global__ __launch_bounds__(128) void finqkv(
    const float* __restrict__ qp, const float* __restrict__ kp,
    const float* __restrict__ vp, const float* __restrict__ cosb,
    const float* __restrict__ sinb, const float* __restrict__ qw,
    const float* __restrict__ kw, float* __restrict__ qn,
    float* __restrict__ kn, float* __restrict__ vn) {
  const int b = blockIdx.x, h = blockIdx.y, d = threadIdx.x;
  float x = 0.f;
  if (h < 32) {
    #pragma unroll
    for (int c = 0; c < 5; ++c) x += qp[(size_t)(c * 32 + b) * 4096 + h * 128 + d];
  } else if (h < 40) {
    #pragma unroll
    for (int c = 0; c < 5; ++c) x += kp[(size_t)(c * 32 + b) * 1024 + (h - 32) * 128 + d];
  } else {
    #pragma unroll
    for (int c = 0; c < 5; ++c) x += vp[(size_t)(c * 32 + b) * 1024 + (h - 40) * 128 + d];
  }
  if (h >= 40) { vn[((size_t)b * 8 + (h - 40)) * 128 + d] = x; return; }

  __shared__ float red[2];
  __shared__ float sh[128];
  float ss = x * x;
  #pragma unroll
  for (int mk = 1; mk < 64; mk <<= 1) ss += __shfl_xor(ss, mk);
  if ((d & 63) == 0) red[d >> 6] = ss;
  __syncthreads();
  const float inv = rsqrtf((red[0] + red[1]) * (1.f / 128.f) + 1e-6f);
  const float* nw = (h < 32) ? qw : kw;
  const float xn = x * inv * nw[d];
  sh[d] = xn;
  __syncthreads();
  const float rot = (d < 64) ? -sh[d + 64] : sh[d - 64];
  const float o = xn * cosb[b * 128 + d] + rot * sinb[b * 128 + d];
  if (h < 32) qn[((size_t)b * 32 + h) * 128 + d] = o;
  else        kn[((size_t)b * 8 + (h - 32)) * 128 + d] = o;
}

// ---------------------------------------------------------------------------
// Paged GQA decode attention (R7-proven, verbatim: depth-2 pipeline).
// grid = 256 (b*8+kvh), block = 512 (8 waves = 32 subgroups of 16 lanes).
// Pool tokens [0, len-1); new token merged from ws (pool is NOT mutated).
// ---------------------------------------------------------------------------
__global__ __launch_bounds__(512) void attn(
    const float* __restrict__ Kp, const float* __restrict__ Vp,
    const float* __restrict__ qn, const float* __restrict__ kn,
    const float* __restrict__ vn, const int* __restrict__ pidx,
    const int* __restrict__ lens, float* __restrict__ ao) {
  const int b = blockIdx.x >> 3, kvh = blockIdx.x & 7;
  const int t = threadIdx.x, w = t >> 6, l = t & 63;
  const int sub = l >> 4, di = (l & 15) * 8;
  __shared__ int pages[128];
  __shared__ float mmS[32][4], msS[32][4];
  __shared__ __align__(16) float maccS[32][4][128];
  if (t < 128) pages[t] = pidx[b * 128 + t];
  __syncthreads();
  const int len = lens[b], lim = len - 1;

  float qf[4][8];
  const float SC = 0.08838834764831845f * 1.4426950408889634f;
  #pragma unroll
  for (int g = 0; g < 4; ++g)
    #pragma unroll
    for (int j = 0; j < 8; ++j)
      qf[g][j] = qn[((size_t)b * 32 + kvh * 4 + g) * 128 + di + j] * SC;

  float m[4], se[4], acc[4][8];
  #pragma unroll
  for (int g = 0; g < 4; ++g) {
    m[g] = -INFINITY; se[g] = 0.f;
    #pragma unroll
    for (int j = 0; j < 8; ++j) acc[g][j] = 0.f;
  }

  const int t0 = w * 4 + sub;
  const int nit = (lim + 31) >> 5;

  auto update = [&](const float (&ck)[8], const float (&cv)[8], bool valid) {
    float s[4];
    #pragma unroll
    for (int g = 0; g < 4; ++g) {
      float d8 = 0.f;
      #pragma unroll
      for (int j = 0; j < 8; ++j) d8 += qf[g][j] * ck[j];
      s[g] = d8;
    }
    #pragma unroll
    for (int mk = 1; mk < 16; mk <<= 1) {
      #pragma unroll
      for (int g = 0; g < 4; ++g) s[g] += __shfl_xor(s[g], mk);
    }
    if (valid) {
      #pragma unroll
      for (int g = 0; g < 4; ++g) {
        const float sg = s[g];
        if (sg > m[g]) {
          const float scf = exp2f(m[g] - sg);
          m[g] = sg;
          se[g] = se[g] * scf + 1.f;
          #pragma unroll
          for (int j = 0; j < 8; ++j) acc[g][j] = acc[g][j] * scf + cv[j];
        } else {
          const float p = exp2f(sg - m[g]);
          se[g] += p;
          #pragma unroll
          for (int j = 0; j < 8; ++j) acc[g][j] += p * cv[j];
        }
      }
    }
  };

  f32x4 ka0, ka1, va0, va1, kb0, kb1, vb0, vb1;
  {
    int tt = min(t0, lim - 1);
    size_t a = ((size_t)pages[tt >> 4] * 16 + (tt & 15)) * 1024 + kvh * 128 + di;
    ka0 = *(const f32x4*)(Kp + a); ka1 = *(const f32x4*)(Kp + a + 4);
    va0 = *(const f32x4*)(Vp + a); va1 = *(const f32x4*)(Vp + a + 4);
  }
  if (nit > 1) {
    int tt = min(32 + t0, lim - 1);
    size_t a = ((size_t)pages[tt >> 4] * 16 + (tt & 15)) * 1024 + kvh * 128 + di;
    kb0 = *(const f32x4*)(Kp + a); kb1 = *(const f32x4*)(Kp + a + 4);
    vb0 = *(const f32x4*)(Vp + a); vb1 = *(const f32x4*)(Vp + a + 4);
  }
  for (int it = 0; it < nit; it += 2) {
    {
      const float ck[8] = {ka0[0], ka0[1], ka0[2], ka0[3], ka1[0], ka1[1], ka1[2], ka1[3]};
      const float cv[8] = {va0[0], va0[1], va0[2], va0[3], va1[0], va1[1], va1[2], va1[3]};
      if (it + 2 < nit) {
        int tt = min((it + 2) * 32 + t0, lim - 1);
        size_t a = ((size_t)pages[tt >> 4] * 16 + (tt & 15)) * 1024 + kvh * 128 + di;
        ka0 = *(const f32x4*)(Kp + a); ka1 = *(const f32x4*)(Kp + a + 4);
        va0 = *(const f32x4*)(Vp + a); va1 = *(const f32x4*)(Vp + a + 4);
      }
      update(ck, cv, it * 32 + t0 < lim);
    }
    if (it + 1 < nit) {
      const float ck[8] = {kb0[0], kb0[1], kb0[2], kb0[3], kb1[0], kb1[1], kb1[2], kb1[3]};
      const float cv[8] = {vb0[0], vb0[1], vb0[2], vb0[3], vb1[0], vb1[1], vb1[2], vb1[3]};
      if (it + 3 < nit) {
        int tt = min((it + 3) * 32 + t0, lim - 1);
        size_t a = ((size_t)pages[tt >> 4] * 16 + (tt & 15)) * 1024 + kvh * 128 + di;
        kb0 = *(const f32x4*)(Kp + a); kb1 = *(const f32x4*)(Kp + a + 4);
        vb0 = *(const f32x4*)(Vp + a); vb1 = *(const f32x4*)(Vp + a + 4);
      }
      update(ck, cv, (it + 1) * 32 + t0 < lim);
    }
  }

  if (w == 0) {                       // new decode token (position len-1)
    const float* kr = kn + ((size_t)b * 8 + kvh) * 128 + di;
    const float* vr = vn + ((size_t)b * 8 + kvh) * 128 + di;
    float ck[8], cv[8];
    #pragma unroll
    for (int j = 0; j < 8; ++j) { ck[j] = kr[j]; cv[j] = vr[j]; }
    update(ck, cv, sub == 0);
  }

  const int st = w * 4 + sub;
  if ((l & 15) == 0) {
    #pragma unroll
    for (int g = 0; g < 4; ++g) { mmS[st][g] = m[g]; msS[st][g] = se[g]; }
  }
  #pragma unroll
  for (int g = 0; g < 4; ++g)
    #pragma unroll
    for (int j = 0; j < 8; ++j) maccS[st][g][di + j] = acc[g][j];
  __syncthreads();

  const int g = t >> 7, dd = t & 127;
  float M = -INFINITY;
  #pragma unroll
  for (int s2 = 0; s2 < 32; ++s2) M = fmaxf(M, mmS[s2][g]);
  float den = 0.f, num = 0.f;
  for (int s2 = 0; s2 < 32; ++s2) {
    const float wg = exp2f(mmS[s2][g] - M);
    den += wg * msS[s2][g];
    num += wg * maccS[s2][g][dd];
  }
  ao[((size_t)b * 32 + kvh * 4 + g) * 128 + dd] = num / den;
}

// ---------------------------------------------------------------------------
extern "C" void kernel_launch(void* const* d_in, const int* in_sizes, int n_in,
                              void* d_out, int out_size, void* d_ws, size_t ws_size,
                              hipStream_t stream) {
  const float* x    = (const float*)d_in[0];
  const float* cosb = (const float*)d_in[1];
  const float* sinb = (const float*)d_in[2];
  const float* Wq   = (const float*)d_in[3];
  const float* Wk   = (const float*)d_in[4];
  const float* Wv   = (const float*)d_in[5];
  const float* Wo   = (const float*)d_in[6];
  const float* qw   = (const float*)d_in[7];
  const float* kw   = (const float*)d_in[8];
  const float* Kp   = (const float*)d_in[9];
  const float* Vp   = (const float*)d_in[10];
  const int*   pidx = (const int*)d_in[11];
  const int*   lens = (const int*)d_in[12];
  float* y = (float*)d_out;

  // ws layout (floats)
  float* ws = (float*)d_ws;
  float* qp = ws;                     // [5][32][4096]
  float* kp = qp + 655360;            // [5][32][1024]
  float* vp = kp + 163840;            // [5][32][1024]
  float* qn = vp + 163840;            // [32][32][128]
  float* kn = qn + 131072;            // [32][8][128]
  float* vn = kn + 32768;             // [32][8][128]
  float* ao = vn + 32768;             // [32][32*128]
  (void)in_sizes; (void)n_in; (void)out_size; (void)ws_size;

  hipMemsetAsync(y, 0, (size_t)32 * 2560 * sizeof(float), stream);
  qkv_gemm<<<dim3(96, 5), 256, 0, stream>>>(x, Wq, Wk, Wv, qp, kp, vp);
  finqkv<<<dim3(32, 48), 128, 0, stream>>>(qp, kp, vp, cosb, sinb, qw, kw, qn, kn, vn);
  attn<<<256, 512, 0, stream>>>(Kp, Vp, qn, kn, vn, pidx, lens, ao);
  o_gemm_a<<<dim3(40, 8), 256, 0, stream>>>(ao, Wo, y);
}

// Round 15
// 96.501 us; speedup vs baseline: 1.0434x; 1.0434x over previous
//
#include <hip/hip_runtime.h>
#include <math.h>

// Problem constants (Qwen3-4B-like decode)
#define NB    32      // batch / total_q
#define HIDV  2560    // hidden size
#define HD    128     // head dim
#define NQH   32      // q heads
#define NKVH  8       // kv heads
// pool: (4096 pages, 16 slots, 8 kvh, 128 d)

typedef __bf16 bf16x8 __attribute__((ext_vector_type(8)));
typedef float  f32x4  __attribute__((ext_vector_type(4)));

__device__ __forceinline__ unsigned bfpack(float a, float b) {
  unsigned ua = __float_as_uint(a), ub = __float_as_uint(b);
  ua = (ua + 0x7FFFu + ((ua >> 16) & 1u)) >> 16;   // RNE to bf16
  ub = (ub + 0x7FFFu + ((ub >> 16) & 1u)) >> 16;
  return ua | (ub << 16);
}

// ---------------------------------------------------------------------------
// Partial GEMM body: P[kc0][b][f] = sum_{k in 2 slabs of chunk kc0} X[b][k]*W[f][k]
// X: (32 x K) fp32 row-major, W: (N x K) fp32 row-major. bf16 MFMA inside.
// Grid stays wide (>=256 blocks): per-block BW is ~150 GB/s, so block count
// is the aggregate-BW lever (R6 lesson: grid 96/40 full-K was +39 us).
// ---------------------------------------------------------------------------
__device__ __forceinline__ void gemm_body(
    const float* __restrict__ X, const float* __restrict__ W,
    float* __restrict__ P, int N, int K, int f0, int kc0, int slabs, int t,
    unsigned short* Wl, unsigned short* Xl) {
  const int w = t >> 6, l = t & 63;
  const int rA = l & 15, kq = l >> 4;
  f32x4 acc0 = {0.f, 0.f, 0.f, 0.f}, acc1 = {0.f, 0.f, 0.f, 0.f};

  for (int s = 0; s < slabs; ++s) {
    const int kc = kc0 * slabs + s;
    if (s) __syncthreads();                  // LDS reuse guard
    const float* Wg = W + (size_t)f0 * K + (size_t)kc * 256;
    #pragma unroll
    for (int i = 0; i < 16; ++i) {           // 64x256 fp32 -> bf16 LDS
      int idx = i * 256 + t;
      int row = idx >> 6, c4 = idx & 63;
      float4 w4 = *(const float4*)(Wg + (size_t)row * K + c4 * 4);
      *(uint2*)((char*)Wl + row * 528 + c4 * 8) =
          make_uint2(bfpack(w4.x, w4.y), bfpack(w4.z, w4.w));
    }
    const float* Xg = X + (size_t)kc * 256;
    #pragma unroll
    for (int i = 0; i < 8; ++i) {            // 32x256 fp32 -> bf16 LDS
      int idx = i * 256 + t;
      int row = idx >> 6, c4 = idx & 63;
      float4 x4 = *(const float4*)(Xg + (size_t)row * K + c4 * 4);
      *(uint2*)((char*)Xl + row * 528 + c4 * 8) =
          make_uint2(bfpack(x4.x, x4.y), bfpack(x4.z, x4.w));
    }
    __syncthreads();

    const char* pa0 = (const char*)Xl + rA * 528 + kq * 16;
    const char* pa1 = pa0 + 16 * 528;
    const char* pb  = (const char*)Wl + (w * 16 + rA) * 528 + kq * 16;
    #pragma unroll
    for (int ks = 0; ks < 8; ++ks) {
      bf16x8 a0 = *(const bf16x8*)(pa0 + ks * 64);
      bf16x8 a1 = *(const bf16x8*)(pa1 + ks * 64);
      bf16x8 bb = *(const bf16x8*)(pb  + ks * 64);
      acc0 = __builtin_amdgcn_mfma_f32_16x16x32_bf16(a0, bb, acc0, 0, 0, 0);
      acc1 = __builtin_amdgcn_mfma_f32_16x16x32_bf16(a1, bb, acc1, 0, 0, 0);
    }
  }
  // C/D layout: col = lane&15 (feature), row = (lane>>4)*4 + j (batch)
  const int fcol = f0 + w * 16 + rA;
  float* Pr = P + ((size_t)kc0 * 32) * N + fcol;
  #pragma unroll
  for (int j = 0; j < 4; ++j) {
    int b0 = kq * 4 + j;
    Pr[(size_t)b0 * N]        = acc0[j];
    Pr[(size_t)(b0 + 16) * N] = acc1[j];
  }
}

// Fused QKV projection: grid (96, 5), chunk = 512 K (2 slabs).
__global__ __launch_bounds__(256) void qkv_gemm(
    const float* __restrict__ X, const float* __restrict__ Wq,
    const float* __restrict__ Wk, const float* __restrict__ Wv,
    float* __restrict__ qp, float* __restrict__ kp, float* __restrict__ vp) {
  __shared__ __align__(16) unsigned short Wl[64 * 264];
  __shared__ __align__(16) unsigned short Xl[32 * 264];
  const int bx = blockIdx.x;
  const float* W; float* P; int N, f0;
  if (bx < 64)      { W = Wq; P = qp; N = 4096; f0 = bx * 64; }
  else if (bx < 80) { W = Wk; P = kp; N = 1024; f0 = (bx - 64) * 64; }
  else              { W = Wv; P = vp; N = 1024; f0 = (bx - 80) * 64; }
  gemm_body(X, W, P, N, 2560, f0, blockIdx.y, 2, threadIdx.x, Wl, Xl);
}

// o_proj GEMM: grid (40, 8), chunk = 512 K (2 slabs).
__global__ __launch_bounds__(256) void o_gemm(
    const float* __restrict__ X, const float* __restrict__ W,
    float* __restrict__ P) {
  __shared__ __align__(16) unsigned short Wl[64 * 264];
  __shared__ __align__(16) unsigned short Xl[32 * 264];
  gemm_body(X, W, P, 2560, 4096, blockIdx.x * 64, blockIdx.y, 2, threadIdx.x, Wl, Xl);
}

// ---------------------------------------------------------------------------
// Reduce 5 K-split partials + RMSNorm (q,k) + RoPE (q,k). grid=(32,48), blk=128.
// ---------------------------------------------------------------------------
__global__ __launch_bounds__(128) void finqkv(
    const float* __restrict__ qp, const float* __restrict__ kp,
    const float* __restrict__ vp, const float* __restrict__ cosb,
    const float* __restrict__ sinb, const float* __restrict__ qw,
    const float* __restrict__ kw, float* __restrict__ qn,
    float* __restrict__ kn, float* __restrict__ vn) {
  const int b = blockIdx.x, h = blockIdx.y, d = threadIdx.x;
  float x = 0.f;
  if (h < 32) {
    #pragma unroll
    for (int c = 0; c < 5; ++c) x += qp[(size_t)(c * 32 + b) * 4096 + h * 128 + d];
  } else if (h < 40) {
    #pragma unroll
    for (int c = 0; c < 5; ++c) x += kp[(size_t)(c * 32 + b) * 1024 + (h - 32) * 128 + d];
  } else {
    #pragma unroll
    for (int c = 0; c < 5; ++c) x += vp[(size_t)(c * 32 + b) * 1024 + (h - 40) * 128 + d];
  }
  if (h >= 40) { vn[((size_t)b * 8 + (h - 40)) * 128 + d] = x; return; }

  __shared__ float red[2];
  __shared__ float sh[128];
  float ss = x * x;
  #pragma unroll
  for (int mk = 1; mk < 64; mk <<= 1) ss += __shfl_xor(ss, mk);
  if ((d & 63) == 0) red[d >> 6] = ss;
  __syncthreads();
  const float inv = rsqrtf((red[0] + red[1]) * (1.f / 128.f) + 1e-6f);
  const float* nw = (h < 32) ? qw : kw;
  const float xn = x * inv * nw[d];
  sh[d] = xn;
  __syncthreads();
  const float rot = (d < 64) ? -sh[d + 64] : sh[d - 64];
  const float o = xn * cosb[b * 128 + d] + rot * sinb[b * 128 + d];
  if (h < 32) qn[((size_t)b * 32 + h) * 128 + d] = o;
  else        kn[((size_t)b * 8 + (h - 32)) * 128 + d] = o;
}

// ---------------------------------------------------------------------------
// Paged GQA decode attention (depth-2 pipeline).
// grid = 256 (b*8+kvh), block = 512 (8 waves = 32 subgroups of 16 lanes).
// Pool tokens [0, len-1); new token merged from ws (pool is NOT mutated).
// ---------------------------------------------------------------------------
__global__ __launch_bounds__(512) void attn(
    const float* __restrict__ Kp, const float* __restrict__ Vp,
    const float* __restrict__ qn, const float* __restrict__ kn,
    const float* __restrict__ vn, const int* __restrict__ pidx,
    const int* __restrict__ lens, float* __restrict__ ao) {
  const int b = blockIdx.x >> 3, kvh = blockIdx.x & 7;
  const int t = threadIdx.x, w = t >> 6, l = t & 63;
  const int sub = l >> 4, di = (l & 15) * 8;
  __shared__ int pages[128];
  __shared__ float mmS[32][4], msS[32][4];
  __shared__ __align__(16) float maccS[32][4][128];
  if (t < 128) pages[t] = pidx[b * 128 + t];
  __syncthreads();
  const int len = lens[b], lim = len - 1;   // pool tokens: [0, lim)

  float qf[4][8];
  const float SC = 0.08838834764831845f * 1.4426950408889634f; // 1/sqrt(128)*log2(e)
  #pragma unroll
  for (int g = 0; g < 4; ++g)
    #pragma unroll
    for (int j = 0; j < 8; ++j)
      qf[g][j] = qn[((size_t)b * 32 + kvh * 4 + g) * 128 + di + j] * SC;

  float m[4], se[4], acc[4][8];
  #pragma unroll
  for (int g = 0; g < 4; ++g) {
    m[g] = -INFINITY; se[g] = 0.f;
    #pragma unroll
    for (int j = 0; j < 8; ++j) acc[g][j] = 0.f;
  }

  const int t0 = w * 4 + sub;
  const int nit = (lim + 31) >> 5;          // 32 tokens per block-iter

  // online-softmax update for one token's K/V held in ck/cv
  auto update = [&](const float (&ck)[8], const float (&cv)[8], bool valid) {
    float s[4];
    #pragma unroll
    for (int g = 0; g < 4; ++g) {
      float d8 = 0.f;
      #pragma unroll
      for (int j = 0; j < 8; ++j) d8 += qf[g][j] * ck[j];
      s[g] = d8;
    }
    #pragma unroll
    for (int mk = 1; mk < 16; mk <<= 1) {
      #pragma unroll
      for (int g = 0; g < 4; ++g) s[g] += __shfl_xor(s[g], mk);
    }
    if (valid) {
      #pragma unroll
      for (int g = 0; g < 4; ++g) {
        const float sg = s[g];
        if (sg > m[g]) {
          const float scf = exp2f(m[g] - sg);
          m[g] = sg;
          se[g] = se[g] * scf + 1.f;
          #pragma unroll
          for (int j = 0; j < 8; ++j) acc[g][j] = acc[g][j] * scf + cv[j];
        } else {
          const float p = exp2f(sg - m[g]);
          se[g] += p;
          #pragma unroll
          for (int j = 0; j < 8; ++j) acc[g][j] += p * cv[j];
        }
      }
    }
  };

  // depth-2 software pipeline, static register names (A/B)
  f32x4 ka0, ka1, va0, va1, kb0, kb1, vb0, vb1;
  {
    int tt = min(t0, lim - 1);
    size_t a = ((size_t)pages[tt >> 4] * 16 + (tt & 15)) * 1024 + kvh * 128 + di;
    ka0 = *(const f32x4*)(Kp + a); ka1 = *(const f32x4*)(Kp + a + 4);
    va0 = *(const f32x4*)(Vp + a); va1 = *(const f32x4*)(Vp + a + 4);
  }
  if (nit > 1) {
    int tt = min(32 + t0, lim - 1);
    size_t a = ((size_t)pages[tt >> 4] * 16 + (tt & 15)) * 1024 + kvh * 128 + di;
    kb0 = *(const f32x4*)(Kp + a); kb1 = *(const f32x4*)(Kp + a + 4);
    vb0 = *(const f32x4*)(Vp + a); vb1 = *(const f32x4*)(Vp + a + 4);
  }
  for (int it = 0; it < nit; it += 2) {
    {
      const float ck[8] = {ka0[0], ka0[1], ka0[2], ka0[3], ka1[0], ka1[1], ka1[2], ka1[3]};
      const float cv[8] = {va0[0], va0[1], va0[2], va0[3], va1[0], va1[1], va1[2], va1[3]};
      if (it + 2 < nit) {
        int tt = min((it + 2) * 32 + t0, lim - 1);
        size_t a = ((size_t)pages[tt >> 4] * 16 + (tt & 15)) * 1024 + kvh * 128 + di;
        ka0 = *(const f32x4*)(Kp + a); ka1 = *(const f32x4*)(Kp + a + 4);
        va0 = *(const f32x4*)(Vp + a); va1 = *(const f32x4*)(Vp + a + 4);
      }
      update(ck, cv, it * 32 + t0 < lim);
    }
    if (it + 1 < nit) {
      const float ck[8] = {kb0[0], kb0[1], kb0[2], kb0[3], kb1[0], kb1[1], kb1[2], kb1[3]};
      const float cv[8] = {vb0[0], vb0[1], vb0[2], vb0[3], vb1[0], vb1[1], vb1[2], vb1[3]};
      if (it + 3 < nit) {
        int tt = min((it + 3) * 32 + t0, lim - 1);
        size_t a = ((size_t)pages[tt >> 4] * 16 + (tt & 15)) * 1024 + kvh * 128 + di;
        kb0 = *(const f32x4*)(Kp + a); kb1 = *(const f32x4*)(Kp + a + 4);
        vb0 = *(const f32x4*)(Vp + a); vb1 = *(const f32x4*)(Vp + a + 4);
      }
      update(ck, cv, (it + 1) * 32 + t0 < lim);
    }
  }

  // New decode token (position len-1), from workspace; owned by (w=0,sub=0)
  if (w == 0) {
    const float* kr = kn + ((size_t)b * 8 + kvh) * 128 + di;
    const float* vr = vn + ((size_t)b * 8 + kvh) * 128 + di;
    float ck[8], cv[8];
    #pragma unroll
    for (int j = 0; j < 8; ++j) { ck[j] = kr[j]; cv[j] = vr[j]; }
    update(ck, cv, sub == 0);
  }

  // Merge the 32 partial states
  const int st = w * 4 + sub;
  if ((l & 15) == 0) {
    #pragma unroll
    for (int g = 0; g < 4; ++g) { mmS[st][g] = m[g]; msS[st][g] = se[g]; }
  }
  #pragma unroll
  for (int g = 0; g < 4; ++g)
    #pragma unroll
    for (int j = 0; j < 8; ++j) maccS[st][g][di + j] = acc[g][j];
  __syncthreads();

  const int g = t >> 7, dd = t & 127;       // 512 threads = 4 g x 128 d
  float M = -INFINITY;
  #pragma unroll
  for (int s2 = 0; s2 < 32; ++s2) M = fmaxf(M, mmS[s2][g]);
  float den = 0.f, num = 0.f;
  for (int s2 = 0; s2 < 32; ++s2) {
    const float wg = exp2f(mmS[s2][g] - M);
    den += wg * msS[s2][g];
    num += wg * maccS[s2][g][dd];
  }
  ao[((size_t)b * 32 + kvh * 4 + g) * 128 + dd] = num / den;
}

// ---------------------------------------------------------------------------
// o_proj partial reduce: y[i] = sum_{c<8} op[c][i], i in [0, 32*2560)
// ---------------------------------------------------------------------------
__global__ __launch_bounds__(256) void oreduce(const float* __restrict__ op,
                                               float* __restrict__ y) {
  const int i = blockIdx.x * 256 + threadIdx.x;
  float s = 0.f;
  #pragma unroll
  for (int c = 0; c < 8; ++c) s += op[(size_t)c * (32 * 2560) + i];
  y[i] = s;
}

// ---------------------------------------------------------------------------
extern "C" void kernel_launch(void* const* d_in, const int* in_sizes, int n_in,
                              void* d_out, int out_size, void* d_ws, size_t ws_size,
                              hipStream_t stream) {
  const float* x    = (const float*)d_in[0];
  const float* cosb = (const float*)d_in[1];
  const float* sinb = (const float*)d_in[2];
  const float* Wq   = (const float*)d_in[3];
  const float* Wk   = (const float*)d_in[4];
  const float* Wv   = (const float*)d_in[5];
  const float* Wo   = (const float*)d_in[6];
  const float* qw   = (const float*)d_in[7];
  const float* kw   = (const float*)d_in[8];
  const float* Kp   = (const float*)d_in[9];
  const float* Vp   = (const float*)d_in[10];
  const int*   pidx = (const int*)d_in[11];
  const int*   lens = (const int*)d_in[12];
  float* y = (float*)d_out;

  // ws layout (floats). op aliases qp (qp consumed by finqkv before o-proj).
  float* ws = (float*)d_ws;
  float* qp = ws;                     // [5][32][4096] (op alias: [8][32][2560])
  float* kp = qp + 655360;            // [5][32][1024]
  float* vp = kp + 163840;            // [5][32][1024]
  float* qn = vp + 163840;            // [32][32][128]
  float* kn = qn + 131072;            // [32][8][128]
  float* vn = kn + 32768;             // [32][8][128]
  float* ao = vn + 32768;             // [32][32*128]
  float* op = qp;                     // reuse
  (void)in_sizes; (void)n_in; (void)out_size; (void)ws_size;

  qkv_gemm<<<dim3(96, 5), 256, 0, stream>>>(x, Wq, Wk, Wv, qp, kp, vp);
  finqkv<<<dim3(32, 48), 128, 0, stream>>>(qp, kp, vp, cosb, sinb, qw, kw, qn, kn, vn);
  attn<<<256, 512, 0, stream>>>(Kp, Vp, qn, kn, vn, pidx, lens, ao);
  o_gemm<<<dim3(40, 8), 256, 0, stream>>>(ao, Wo, op);
  oreduce<<<320, 256, 0, stream>>>(op, y);
}